// Round 5
// baseline (6509.839 us; speedup 1.0000x reference)
//
#include <hip/hip_runtime.h>
#include <hip/hip_bf16.h>

#define EPS 1e-5f
#define Bn 8
#define Cn 512
#define Nn 2304
#define C1n 256
#define C2n 256
#define CGn 128

typedef __bf16 bf16_t;
typedef __bf16 bf16x8 __attribute__((ext_vector_type(8)));
typedef float f32x4 __attribute__((ext_vector_type(4)));

#define MFMA16(a, b, c) __builtin_amdgcn_mfma_f32_16x16x32_bf16(a, b, c, 0, 0, 0)

// ---------- WPAR element offsets (bf16 weight arena) ----------
static constexpr size_t P_TW = 0;            // (4,256,512) 524288
static constexpr size_t P_TB = 524288;       // 1024
static constexpr size_t P_PW = 525312;       // 524288
static constexpr size_t P_PB = 1049600;      // 1024
static constexpr size_t P_GW = 1050624;      // 524288
static constexpr size_t P_GB = 1574912;      // 1024
static constexpr size_t P_WW = 1575936;      // (4,128,256) 131072
static constexpr size_t P_WB = 1707008;      // 512
static constexpr size_t P_WG = 1707520;      // 512
static constexpr size_t P_WBE = 1708032;     // 512
static constexpr size_t P_BCW = 1708544;     // (512,1024) 524288
static constexpr size_t P_BCB = 2232832;     // 512
static constexpr size_t P_BCG = 2233344;     // 512
static constexpr size_t P_BCBE = 2233856;    // 512
static constexpr size_t P_TOT = 2234368;     // elems

// ---------- workspace layout (bytes); total ~33.9 MB ----------
static constexpr size_t OFF_WPAR  = 0;          // 4,468,736
static constexpr size_t OFF_BCWF  = 4468736;    // bf16 524288 -> 1,048,576
static constexpr size_t OFF_BIASF = 5517312;    // f32[512] 2048
static constexpr size_t OFF_SW    = 5519360;    // f32[512]
static constexpr size_t OFF_TW2   = 5521408;
static constexpr size_t OFF_SO    = 5523456;
static constexpr size_t OFF_TO    = 5525504;
static constexpr size_t OFF_STATW = 5527552;    // f64[1024] 8192 (memset)
static constexpr size_t OFF_STATO = 5535744;    // f64[1024] 8192
static constexpr size_t OFF_PART  = 5543936;    // f64[288*1024] 2,359,296
static constexpr size_t OFF_WY    = 7903232;    // bf16 (B,N,512) 18,874,368
static constexpr size_t OFF_Q     = 26777600;   // bf16 (2,N,256) 2,359,296
static constexpr size_t OFF_K     = 29136896;   // bf16 (2,N,256) 2,359,296
static constexpr size_t OFF_V     = 31496192;   // bf16 (2,256,N) 2,359,296
                                                // end 33,855,488

// ---------- K0: convert 14 f32 weight inputs -> bf16 WPAR ----------
struct WArgs {
  const float* src[14];
  unsigned n[14];
  unsigned off[14];
};

__global__ __launch_bounds__(256) void k_wconv(WArgs a, bf16_t* __restrict__ par) {
  int which = blockIdx.y;
  const float* s = a.src[which];
  unsigned n = a.n[which];
  bf16_t* dst = par + a.off[which];
  size_t stride = (size_t)gridDim.x * blockDim.x;
  for (size_t i = (size_t)blockIdx.x * blockDim.x + threadIdx.x; i < n; i += stride)
    dst[i] = (bf16_t)s[i];
}

// ---------- K1a: theta/phi projection for (g, batch-pair) ----------
// Q[m][o] = sum_c x[c][m] * W[o][c] + b[o];  feats is f32 (B,C,N)
__global__ __launch_bounds__(256) void k_proj_qk(
    const float* __restrict__ feats, const bf16_t* __restrict__ par,
    bf16_t* __restrict__ Qb, bf16_t* __restrict__ Kb, int g, int bp) {
  __shared__ alignas(16) bf16_t xsT[64][40];  // [n-pos][c-chunk], 16B-aligned rows
  int p = blockIdx.z >> 1, bl = blockIdx.z & 1, b = bp * 2 + bl;
  const bf16_t* W = par + (p == 0 ? P_TW : P_PW) + (size_t)g * C1n * Cn;
  const bf16_t* bias = par + (p == 0 ? P_TB : P_PB) + g * C1n;
  bf16_t* out = (p == 0 ? Qb : Kb) + (size_t)bl * Nn * C1n;

  int tid = threadIdx.x, w = tid >> 6, lane = tid & 63;
  int l15 = lane & 15, quad = lane >> 4;
  int m0 = blockIdx.x * 64;
  int o0 = blockIdx.y * 64;

  f32x4 acc[4];
#pragma unroll
  for (int j = 0; j < 4; j++) acc[j] = (f32x4){0.f, 0.f, 0.f, 0.f};

  for (int kk = 0; kk < 16; kk++) {
    int c0 = kk * 32;
    __syncthreads();
#pragma unroll
    for (int i = 0; i < 8; i++) {
      int cc = i * 4 + w;
      xsT[lane][cc] = (bf16_t)feats[((size_t)b * Cn + c0 + cc) * Nn + m0 + lane];
    }
    __syncthreads();
    bf16x8 a = *(const bf16x8*)(&xsT[w * 16 + l15][quad * 8]);
#pragma unroll
    for (int j = 0; j < 4; j++) {
      bf16x8 bw = *(const bf16x8*)(W + (size_t)(o0 + j * 16 + l15) * Cn + c0 + quad * 8);
      acc[j] = MFMA16(a, bw, acc[j]);
    }
  }
#pragma unroll
  for (int j = 0; j < 4; j++) {
    int col = o0 + j * 16 + l15;
    float bv = (float)bias[col];
#pragma unroll
    for (int r = 0; r < 4; r++)
      out[(size_t)(m0 + w * 16 + quad * 4 + r) * C1n + col] = (bf16_t)(acc[j][r] + bv);
  }
}

// ---------- K1b: g projection -> V (2,256,N) for (g, batch-pair) ----------
__global__ __launch_bounds__(256) void k_proj_v(
    const float* __restrict__ feats, const bf16_t* __restrict__ par,
    bf16_t* __restrict__ Vb, int g, int bp) {
  __shared__ alignas(16) bf16_t xsT[64][40];
  int bl = blockIdx.z, b = bp * 2 + bl;
  const bf16_t* W = par + P_GW + (size_t)g * C2n * Cn;
  const bf16_t* bias = par + P_GB + g * C2n;
  bf16_t* out = Vb + (size_t)bl * C2n * Nn;

  int tid = threadIdx.x, w = tid >> 6, lane = tid & 63;
  int l15 = lane & 15, quad = lane >> 4;
  int n0 = blockIdx.x * 64;
  int c20 = blockIdx.y * 64 + w * 16;

  f32x4 acc[4];
#pragma unroll
  for (int j = 0; j < 4; j++) acc[j] = (f32x4){0.f, 0.f, 0.f, 0.f};

  for (int kk = 0; kk < 16; kk++) {
    int c0 = kk * 32;
    __syncthreads();
#pragma unroll
    for (int i = 0; i < 8; i++) {
      int cc = i * 4 + w;
      xsT[lane][cc] = (bf16_t)feats[((size_t)b * Cn + c0 + cc) * Nn + n0 + lane];
    }
    __syncthreads();
    bf16x8 a = *(const bf16x8*)(W + (size_t)(c20 + l15) * Cn + c0 + quad * 8);
#pragma unroll
    for (int j = 0; j < 4; j++) {
      bf16x8 bx = *(const bf16x8*)(&xsT[j * 16 + l15][quad * 8]);
      acc[j] = MFMA16(a, bx, acc[j]);
    }
  }
#pragma unroll
  for (int r = 0; r < 4; r++) {
    int row = c20 + quad * 4 + r;
    float bv = (float)bias[row];
#pragma unroll
    for (int j = 0; j < 4; j++)
      out[(size_t)row * Nn + n0 + j * 16 + l15] = (bf16_t)(acc[j][r] + bv);
  }
}

// ---------- K2: flash attention + fused W-conv for (g, batch-pair) ----------
__global__ __launch_bounds__(256) void k_attn_wy(
    const bf16_t* __restrict__ Qb, const bf16_t* __restrict__ Kb,
    const bf16_t* __restrict__ Vb, const bf16_t* __restrict__ par,
    bf16_t* __restrict__ wyBF, int g, int bp) {
  __shared__ alignas(16) bf16_t pbuf[4][16 * 40];
  __shared__ alignas(16) bf16_t ybuf[4][16 * 264];
  int bl = blockIdx.y, b = bp * 2 + bl;
  const bf16_t* Qp = Qb + (size_t)bl * Nn * C1n;
  const bf16_t* Kp = Kb + (size_t)bl * Nn * C1n;
  const bf16_t* Vp = Vb + (size_t)bl * C2n * Nn;

  int tid = threadIdx.x, w = tid >> 6, lane = tid & 63;
  int l15 = lane & 15, quad = lane >> 4;
  int m0 = blockIdx.x * 64 + w * 16;

  bf16x8 qf[8];
  const bf16_t* qrow = Qp + (size_t)(m0 + l15) * C1n + quad * 8;
#pragma unroll
  for (int kk = 0; kk < 8; kk++) qf[kk] = *(const bf16x8*)(qrow + kk * 32);

  f32x4 oacc[16];
#pragma unroll
  for (int ct = 0; ct < 16; ct++) oacc[ct] = (f32x4){0.f, 0.f, 0.f, 0.f};
  float mrun[4], lrun[4];
#pragma unroll
  for (int r = 0; r < 4; r++) { mrun[r] = -1e30f; lrun[r] = 0.f; }

  bf16_t* pw = pbuf[w];
  const float L2E = 1.44269504088896f;

  for (int n0 = 0; n0 < Nn; n0 += 32) {
    f32x4 s0 = (f32x4){0.f, 0.f, 0.f, 0.f};
    f32x4 s1 = (f32x4){0.f, 0.f, 0.f, 0.f};
    const bf16_t* k0p = Kp + (size_t)(n0 + l15) * C1n + quad * 8;
    const bf16_t* k1p = k0p + 16 * C1n;
#pragma unroll
    for (int kk = 0; kk < 8; kk++) {
      s0 = MFMA16(qf[kk], *(const bf16x8*)(k0p + kk * 32), s0);
      s1 = MFMA16(qf[kk], *(const bf16x8*)(k1p + kk * 32), s1);
    }
    float mnew[4], alpha[4];
#pragma unroll
    for (int r = 0; r < 4; r++) {
      s0[r] *= 0.0625f;  // c1^-0.5
      s1[r] *= 0.0625f;
      float t = fmaxf(s0[r], s1[r]);
      t = fmaxf(t, __shfl_xor(t, 1));
      t = fmaxf(t, __shfl_xor(t, 2));
      t = fmaxf(t, __shfl_xor(t, 4));
      t = fmaxf(t, __shfl_xor(t, 8));
      mnew[r] = fmaxf(mrun[r], t);
      alpha[r] = exp2f((mrun[r] - mnew[r]) * L2E);
    }
#pragma unroll
    for (int r = 0; r < 4; r++) {
      s0[r] = exp2f((s0[r] - mnew[r]) * L2E);
      s1[r] = exp2f((s1[r] - mnew[r]) * L2E);
      float rsum = s0[r] + s1[r];
      rsum += __shfl_xor(rsum, 1);
      rsum += __shfl_xor(rsum, 2);
      rsum += __shfl_xor(rsum, 4);
      rsum += __shfl_xor(rsum, 8);
      lrun[r] = lrun[r] * alpha[r] + rsum;
      mrun[r] = mnew[r];
    }
#pragma unroll
    for (int ct = 0; ct < 16; ct++)
#pragma unroll
      for (int r = 0; r < 4; r++) oacc[ct][r] *= alpha[r];
    // C-layout -> A-layout via LDS round trip
    __syncthreads();
#pragma unroll
    for (int r = 0; r < 4; r++) {
      pw[(quad * 4 + r) * 40 + l15] = (bf16_t)s0[r];
      pw[(quad * 4 + r) * 40 + 16 + l15] = (bf16_t)s1[r];
    }
    __syncthreads();
    bf16x8 pa = *(const bf16x8*)(pw + l15 * 40 + quad * 8);
    const bf16_t* vbase = Vp + (size_t)l15 * Nn + n0 + quad * 8;
#pragma unroll
    for (int ct = 0; ct < 16; ct++) {
      bf16x8 vb = *(const bf16x8*)(vbase + (size_t)ct * 16 * Nn);
      oacc[ct] = MFMA16(pa, vb, oacc[ct]);
    }
  }
  float inv[4];
#pragma unroll
  for (int r = 0; r < 4; r++) inv[r] = 1.f / lrun[r];

  // fused W-conv: wy[m][o] = sum_c y[m][c] w_w[o][c]
  bf16_t* yb = ybuf[w];
  const bf16_t* Wg = par + P_WW + (size_t)g * CGn * C2n;
  const bf16_t* wbias = par + P_WB + g * CGn;
  __syncthreads();
#pragma unroll
  for (int ct = 0; ct < 16; ct++)
#pragma unroll
    for (int r = 0; r < 4; r++)
      yb[(quad * 4 + r) * 264 + ct * 16 + l15] = (bf16_t)(oacc[ct][r] * inv[r]);
  __syncthreads();

  f32x4 wyacc[8];
#pragma unroll
  for (int j = 0; j < 8; j++) wyacc[j] = (f32x4){0.f, 0.f, 0.f, 0.f};
#pragma unroll
  for (int kk = 0; kk < 8; kk++) {
    bf16x8 ya = *(const bf16x8*)(yb + l15 * 264 + kk * 32 + quad * 8);
#pragma unroll
    for (int j = 0; j < 8; j++) {
      bf16x8 wb = *(const bf16x8*)(Wg + (size_t)(j * 16 + l15) * C2n + kk * 32 + quad * 8);
      wyacc[j] = MFMA16(ya, wb, wyacc[j]);
    }
  }
#pragma unroll
  for (int j = 0; j < 8; j++) {
    int o = j * 16 + l15;
    float bv = (float)wbias[o];
#pragma unroll
    for (int r = 0; r < 4; r++)
      wyBF[((size_t)b * Nn + m0 + quad * 4 + r) * 512 + g * 128 + o] =
          (bf16_t)(wyacc[j][r] + bv);
  }
}

// ---------- wy BN stats (channel-last), f64 atomics ----------
__global__ __launch_bounds__(256) void k_wy_stats(const bf16_t* __restrict__ wyBF,
                                                  double* __restrict__ stats) {
  int b = blockIdx.y;
  int m0 = blockIdx.x * 256;
  int tid = threadIdx.x;
  double s0 = 0., q0 = 0., s1 = 0., q1 = 0.;
  const bf16_t* base = wyBF + ((size_t)b * Nn + m0) * 512;
  for (int i = 0; i < 256; i++) {
    double v0 = (double)(float)base[(size_t)i * 512 + tid];
    double v1 = (double)(float)base[(size_t)i * 512 + 256 + tid];
    s0 += v0; q0 += v0 * v0; s1 += v1; q1 += v1 * v1;
  }
  atomicAdd(&stats[tid], s0);
  atomicAdd(&stats[512 + tid], q0);
  atomicAdd(&stats[256 + tid], s1);
  atomicAdd(&stats[768 + tid], q1);
}

// ---------- BN scale/shift ----------
__global__ void k_bn_st(const double* __restrict__ stats, const bf16_t* __restrict__ gamma,
                        const bf16_t* __restrict__ beta, float* __restrict__ sArr,
                        float* __restrict__ tArr, double inv_count) {
  int ch = threadIdx.x;  // 512
  double mean = stats[ch] * inv_count;
  double var = stats[512 + ch] * inv_count - mean * mean;
  double s = (double)(float)gamma[ch] / sqrt(var + (double)EPS);
  sArr[ch] = (float)s;
  tArr[ch] = (float)((double)(float)beta[ch] - mean * s);
}

// ---------- fold wy-BN into bottleneck weights ----------
__global__ __launch_bounds__(256) void k_fold(
    const bf16_t* __restrict__ par, const float* __restrict__ sW,
    const float* __restrict__ tW, bf16_t* __restrict__ bcwF, float* __restrict__ biasF) {
  int oo = blockIdx.x;
  int tid = threadIdx.x;
  const bf16_t* row = par + P_BCW + (size_t)oo * 1024;
  bf16_t* orow = bcwF + (size_t)oo * 1024;
  float part = 0.f;
  for (int c = tid; c < 512; c += 256) orow[c] = row[c];
  for (int c = 512 + tid; c < 1024; c += 256) {
    float wv = (float)row[c];
    orow[c] = (bf16_t)(wv * sW[c - 512]);
    part += wv * tW[c - 512];
  }
  __shared__ float red[256];
  red[tid] = part;
  __syncthreads();
  for (int s = 128; s > 0; s >>= 1) {
    if (tid < s) red[tid] += red[tid + s];
    __syncthreads();
  }
  if (tid == 0) biasF[oo] = (float)par[P_BCB + oo] + red[0];
}

// ---------- final GEMM (two modes): out_pre = bcwF @ [x | wy] + biasF ----------
// mode 0: write per-block stats partials; mode 1: write normalized f32 output
__global__ __launch_bounds__(256) void k_final(
    const float* __restrict__ feats, const bf16_t* __restrict__ wyBF,
    const bf16_t* __restrict__ bcwF, const float* __restrict__ biasF,
    const float* __restrict__ sO, const float* __restrict__ tO,
    double* __restrict__ part, float* __restrict__ out, int mode) {
  __shared__ alignas(16) bf16_t xsT[64][40];
  int b = blockIdx.z;
  int tid = threadIdx.x, w = tid >> 6, lane = tid & 63;
  int l15 = lane & 15, quad = lane >> 4;
  int oo0 = blockIdx.y * 64 + w * 16;
  int n0 = blockIdx.x * 64;

  f32x4 acc[4];
#pragma unroll
  for (int j = 0; j < 4; j++) acc[j] = (f32x4){0.f, 0.f, 0.f, 0.f};

  // first 512 channels: feats via LDS transpose staging
  for (int kk = 0; kk < 16; kk++) {
    int c0 = kk * 32;
    __syncthreads();
#pragma unroll
    for (int i = 0; i < 8; i++) {
      int cc = i * 4 + w;
      xsT[lane][cc] = (bf16_t)feats[((size_t)b * Cn + c0 + cc) * Nn + n0 + lane];
    }
    __syncthreads();
    bf16x8 a = *(const bf16x8*)(bcwF + (size_t)(oo0 + l15) * 1024 + c0 + quad * 8);
#pragma unroll
    for (int j = 0; j < 4; j++) {
      bf16x8 bx = *(const bf16x8*)(&xsT[j * 16 + l15][quad * 8]);
      acc[j] = MFMA16(a, bx, acc[j]);
    }
  }
  // second 512 channels: wy (channel-contiguous) direct
  for (int kk = 0; kk < 16; kk++) {
    int c0 = kk * 32;
    bf16x8 a = *(const bf16x8*)(bcwF + (size_t)(oo0 + l15) * 1024 + 512 + c0 + quad * 8);
#pragma unroll
    for (int j = 0; j < 4; j++) {
      bf16x8 bw = *(const bf16x8*)(wyBF + ((size_t)b * Nn + n0 + j * 16 + l15) * 512 + c0 + quad * 8);
      acc[j] = MFMA16(a, bw, acc[j]);
    }
  }

  if (mode == 0) {
#pragma unroll
    for (int r = 0; r < 4; r++) {
      int row = oo0 + quad * 4 + r;
      float bv = biasF[row];
      float s = 0.f, q = 0.f;
#pragma unroll
      for (int j = 0; j < 4; j++) {
        float v = acc[j][r] + bv;
        s += v; q += v * v;
      }
      s += __shfl_xor(s, 1); q += __shfl_xor(q, 1);
      s += __shfl_xor(s, 2); q += __shfl_xor(q, 2);
      s += __shfl_xor(s, 4); q += __shfl_xor(q, 4);
      s += __shfl_xor(s, 8); q += __shfl_xor(q, 8);
      if (l15 == 0) {
        size_t slot = ((size_t)blockIdx.x * 8 + b) * 1024;
        part[slot + row] = (double)s;
        part[slot + 512 + row] = (double)q;
      }
    }
  } else {
#pragma unroll
    for (int r = 0; r < 4; r++) {
      int row = oo0 + quad * 4 + r;
      float bv = biasF[row];
      float sc = sO[row], tc = tO[row];
#pragma unroll
      for (int j = 0; j < 4; j++)
        out[((size_t)b * 512 + row) * Nn + n0 + j * 16 + l15] =
            (acc[j][r] + bv) * sc + tc;
    }
  }
}

// ---------- reduce out-stats partials ----------
__global__ __launch_bounds__(256) void k_out_reduce(const double* __restrict__ part,
                                                    double* __restrict__ stats) {
  int j = blockIdx.x * 256 + threadIdx.x;  // 0..1023
  double acc = 0.;
  for (int p = 0; p < 288; p++) acc += part[(size_t)p * 1024 + j];
  stats[j] = acc;
}

extern "C" void kernel_launch(void* const* d_in, const int* in_sizes, int n_in,
                              void* d_out, int out_size, void* d_ws, size_t ws_size,
                              hipStream_t stream) {
  const float* feats = (const float*)d_in[0];

  char* ws = (char*)d_ws;
  bf16_t* WPAR = (bf16_t*)(ws + OFF_WPAR);
  bf16_t* bcwF = (bf16_t*)(ws + OFF_BCWF);
  float* biasF = (float*)(ws + OFF_BIASF);
  float* sW = (float*)(ws + OFF_SW);
  float* tW = (float*)(ws + OFF_TW2);
  float* sO = (float*)(ws + OFF_SO);
  float* tO = (float*)(ws + OFF_TO);
  double* statsWy = (double*)(ws + OFF_STATW);
  double* statsO = (double*)(ws + OFF_STATO);
  double* partO = (double*)(ws + OFF_PART);
  bf16_t* wyBF = (bf16_t*)(ws + OFF_WY);
  bf16_t* Qb = (bf16_t*)(ws + OFF_Q);
  bf16_t* Kb = (bf16_t*)(ws + OFF_K);
  bf16_t* Vb = (bf16_t*)(ws + OFF_V);

  static const unsigned par_off[14] = {
      (unsigned)P_TW, (unsigned)P_TB, (unsigned)P_PW, (unsigned)P_PB,
      (unsigned)P_GW, (unsigned)P_GB, (unsigned)P_WW, (unsigned)P_WB,
      (unsigned)P_WG, (unsigned)P_WBE, (unsigned)P_BCW, (unsigned)P_BCB,
      (unsigned)P_BCG, (unsigned)P_BCBE};
  WArgs wa;
  for (int i = 0; i < 14; i++) {
    wa.src[i] = (const float*)d_in[i + 1];
    wa.n[i] = (unsigned)in_sizes[i + 1];
    wa.off[i] = par_off[i];
  }

  hipMemsetAsync(ws + OFF_STATW, 0, 8192, stream);  // statsWy only

  k_wconv<<<dim3(256, 14), 256, 0, stream>>>(wa, WPAR);
  for (int g = 0; g < 4; g++) {
    for (int bp = 0; bp < 4; bp++) {
      k_proj_qk<<<dim3(36, 4, 4), 256, 0, stream>>>(feats, WPAR, Qb, Kb, g, bp);
      k_proj_v<<<dim3(36, 4, 2), 256, 0, stream>>>(feats, WPAR, Vb, g, bp);
      k_attn_wy<<<dim3(36, 2), 256, 0, stream>>>(Qb, Kb, Vb, WPAR, wyBF, g, bp);
    }
  }
  k_wy_stats<<<dim3(9, 8), 256, 0, stream>>>(wyBF, statsWy);
  k_bn_st<<<1, 512, 0, stream>>>(statsWy, WPAR + P_WG, WPAR + P_WBE, sW, tW, 1.0 / 18432.0);
  k_fold<<<512, 256, 0, stream>>>(WPAR, sW, tW, bcwF, biasF);
  k_final<<<dim3(36, 8, 8), 256, 0, stream>>>(feats, wyBF, bcwF, biasF, sO, tO, partO,
                                              (float*)d_out, 0);
  k_out_reduce<<<4, 256, 0, stream>>>(partO, statsO);
  k_bn_st<<<1, 512, 0, stream>>>(statsO, WPAR + P_BCG, WPAR + P_BCBE, sO, tO, 1.0 / 18432.0);
  k_final<<<dim3(36, 8, 8), 256, 0, stream>>>(feats, wyBF, bcwF, biasF, sO, tO, partO,
                                              (float*)d_out, 1);
}

// Round 6
// 2132.899 us; speedup vs baseline: 3.0521x; 3.0521x over previous
//
#include <hip/hip_runtime.h>
#include <hip/hip_bf16.h>

#define EPS 1e-5f
#define Bn 8
#define Cn 512
#define Nn 2304
#define C1n 256
#define C2n 256
#define CGn 128

typedef __bf16 bf16_t;
typedef __bf16 bf16x8 __attribute__((ext_vector_type(8)));
typedef float f32x4 __attribute__((ext_vector_type(4)));

#define MFMA16(a, b, c) __builtin_amdgcn_mfma_f32_16x16x32_bf16(a, b, c, 0, 0, 0)

// ---------- WPAR element offsets (bf16 weight arena) ----------
static constexpr size_t P_TW = 0;            // (4,256,512)
static constexpr size_t P_TB = 524288;
static constexpr size_t P_PW = 525312;
static constexpr size_t P_PB = 1049600;
static constexpr size_t P_GW = 1050624;
static constexpr size_t P_GB = 1574912;
static constexpr size_t P_WW = 1575936;      // (4,128,256)
static constexpr size_t P_WB = 1707008;
static constexpr size_t P_WG = 1707520;
static constexpr size_t P_WBE = 1708032;
static constexpr size_t P_BCW = 1708544;     // (512,1024)
static constexpr size_t P_BCB = 2232832;
static constexpr size_t P_BCG = 2233344;
static constexpr size_t P_BCBE = 2233856;

// ---------- workspace layout (bytes) ----------
static constexpr size_t OFF_WPAR  = 0;          // 4,468,736
static constexpr size_t OFF_BIASF = 4468736;    // f32[512]
static constexpr size_t OFF_SW    = 4470784;
static constexpr size_t OFF_TW2   = 4472832;
static constexpr size_t OFF_SO    = 4474880;
static constexpr size_t OFF_TO    = 4476928;
static constexpr size_t OFF_STATW = 4478976;    // f64[1024] (memset w/ STATO)
static constexpr size_t OFF_STATO = 4487168;    // f64[1024]
static constexpr size_t OFF_WY    = 4495360;    // bf16 (B,N,512) 18,874,368
static constexpr size_t OFF_KV    = 23369728;   // adaptive K/V slot arena; bcwF overlay
static constexpr size_t KVS       = 1179648;    // elems per slot: K (N,256) + V (256,N)
static constexpr size_t KVS_BYTES = 2359296;

// ---------- K0: convert 14 f32 weight inputs -> bf16 WPAR ----------
struct WArgs {
  const float* src[14];
  unsigned n[14];
  unsigned off[14];
};

__global__ __launch_bounds__(256) void k_wconv(WArgs a, bf16_t* __restrict__ par) {
  int which = blockIdx.y;
  const float* s = a.src[which];
  unsigned n = a.n[which];
  bf16_t* dst = par + a.off[which];
  size_t stride = (size_t)gridDim.x * blockDim.x;
  for (size_t i = (size_t)blockIdx.x * blockDim.x + threadIdx.x; i < n; i += stride)
    dst[i] = (bf16_t)s[i];
}

// ---------- K1a: phi projection -> K slot (N,256) ----------
__global__ __launch_bounds__(256) void k_proj_k(
    const float* __restrict__ feats, const bf16_t* __restrict__ par,
    bf16_t* __restrict__ KV, int gb_base) {
  __shared__ alignas(16) bf16_t xsT[64][40];
  int s = blockIdx.z, gb = gb_base + s, g = gb >> 3, b = gb & 7;
  const bf16_t* W = par + P_PW + (size_t)g * C1n * Cn;
  const bf16_t* bias = par + P_PB + g * C1n;
  bf16_t* out = KV + (size_t)s * KVS;

  int tid = threadIdx.x, w = tid >> 6, lane = tid & 63;
  int l15 = lane & 15, quad = lane >> 4;
  int m0 = blockIdx.x * 64;
  int o0 = blockIdx.y * 64;

  f32x4 acc[4];
#pragma unroll
  for (int j = 0; j < 4; j++) acc[j] = (f32x4){0.f, 0.f, 0.f, 0.f};

  for (int kk = 0; kk < 16; kk++) {
    int c0 = kk * 32;
    __syncthreads();
#pragma unroll
    for (int i = 0; i < 8; i++) {
      int cc = i * 4 + w;
      xsT[lane][cc] = (bf16_t)feats[((size_t)b * Cn + c0 + cc) * Nn + m0 + lane];
    }
    __syncthreads();
    bf16x8 a = *(const bf16x8*)(&xsT[w * 16 + l15][quad * 8]);
#pragma unroll
    for (int j = 0; j < 4; j++) {
      bf16x8 bw = *(const bf16x8*)(W + (size_t)(o0 + j * 16 + l15) * Cn + c0 + quad * 8);
      acc[j] = MFMA16(a, bw, acc[j]);
    }
  }
#pragma unroll
  for (int j = 0; j < 4; j++) {
    int col = o0 + j * 16 + l15;
    float bv = (float)bias[col];
#pragma unroll
    for (int r = 0; r < 4; r++)
      out[(size_t)(m0 + w * 16 + quad * 4 + r) * C1n + col] = (bf16_t)(acc[j][r] + bv);
  }
}

// ---------- K1b: g projection -> V slot (256,N) ----------
__global__ __launch_bounds__(256) void k_proj_v(
    const float* __restrict__ feats, const bf16_t* __restrict__ par,
    bf16_t* __restrict__ KV, int gb_base) {
  __shared__ alignas(16) bf16_t xsT[64][40];
  int s = blockIdx.z, gb = gb_base + s, g = gb >> 3, b = gb & 7;
  const bf16_t* W = par + P_GW + (size_t)g * C2n * Cn;
  const bf16_t* bias = par + P_GB + g * C2n;
  bf16_t* out = KV + (size_t)s * KVS + (size_t)Nn * C1n;

  int tid = threadIdx.x, w = tid >> 6, lane = tid & 63;
  int l15 = lane & 15, quad = lane >> 4;
  int n0 = blockIdx.x * 64;
  int c20 = blockIdx.y * 64 + w * 16;

  f32x4 acc[4];
#pragma unroll
  for (int j = 0; j < 4; j++) acc[j] = (f32x4){0.f, 0.f, 0.f, 0.f};

  for (int kk = 0; kk < 16; kk++) {
    int c0 = kk * 32;
    __syncthreads();
#pragma unroll
    for (int i = 0; i < 8; i++) {
      int cc = i * 4 + w;
      xsT[lane][cc] = (bf16_t)feats[((size_t)b * Cn + c0 + cc) * Nn + n0 + lane];
    }
    __syncthreads();
    bf16x8 a = *(const bf16x8*)(W + (size_t)(c20 + l15) * Cn + c0 + quad * 8);
#pragma unroll
    for (int j = 0; j < 4; j++) {
      bf16x8 bx = *(const bf16x8*)(&xsT[j * 16 + l15][quad * 8]);
      acc[j] = MFMA16(a, bx, acc[j]);
    }
  }
#pragma unroll
  for (int r = 0; r < 4; r++) {
    int row = c20 + quad * 4 + r;
    float bv = (float)bias[row];
#pragma unroll
    for (int j = 0; j < 4; j++)
      out[(size_t)row * Nn + n0 + j * 16 + l15] = (bf16_t)(acc[j][r] + bv);
  }
}

// ---------- K2: fused Q-proj + split-K flash attention + W-conv ----------
// block = 16 Q-rows; 4 waves split the N-loop (576 each); in-block LSE merge.
__global__ __launch_bounds__(256) void k_attn_wy(
    const float* __restrict__ feats, const bf16_t* __restrict__ KV,
    const bf16_t* __restrict__ par, bf16_t* __restrict__ wyBF, int gb_base) {
  __shared__ alignas(16) bf16_t xq[16 * 520];      // x^T tile (16 rows x 512 c)
  __shared__ alignas(16) bf16_t qbuf[16 * 264];    // Q A-layout
  __shared__ alignas(16) bf16_t pbuf[4][16 * 40];  // per-wave P round-trip
  __shared__ alignas(16) bf16_t obuf[4][16 * 264]; // scaled O partials
  __shared__ alignas(16) bf16_t ybuf[16 * 264];    // merged y A-layout
  __shared__ float mlbuf[4][16][2];

  int s = blockIdx.y, gb = gb_base + s, g = gb >> 3, b = gb & 7;
  const bf16_t* Kp = KV + (size_t)s * KVS;
  const bf16_t* Vp = KV + (size_t)s * KVS + (size_t)Nn * C1n;

  int tid = threadIdx.x, w = tid >> 6, lane = tid & 63;
  int l15 = lane & 15, quad = lane >> 4;
  int m0 = blockIdx.x * 16;
  const float L2E = 1.44269504088896f;

  // phase 0: stage x^T (16 x 512) bf16
  for (int e = tid; e < 16 * 512; e += 256) {
    int m = e & 15, c = e >> 4;
    xq[m * 520 + c] = (bf16_t)feats[((size_t)b * Cn + c) * Nn + m0 + m];
  }
  __syncthreads();

  // phase 1: Q tile; wave w computes c1-cols [w*64, w*64+64)
  {
    const bf16_t* Wt = par + P_TW + (size_t)g * C1n * Cn;
    const bf16_t* tb = par + P_TB + g * C1n;
    f32x4 qa[4];
#pragma unroll
    for (int j = 0; j < 4; j++) qa[j] = (f32x4){0.f, 0.f, 0.f, 0.f};
#pragma unroll
    for (int kk = 0; kk < 16; kk++) {
      bf16x8 a = *(const bf16x8*)(xq + l15 * 520 + kk * 32 + quad * 8);
#pragma unroll
      for (int j = 0; j < 4; j++) {
        int o = w * 64 + j * 16 + l15;
        bf16x8 bw = *(const bf16x8*)(Wt + (size_t)o * Cn + kk * 32 + quad * 8);
        qa[j] = MFMA16(a, bw, qa[j]);
      }
    }
#pragma unroll
    for (int j = 0; j < 4; j++) {
      int o = w * 64 + j * 16 + l15;
      float bv = (float)tb[o];
#pragma unroll
      for (int r = 0; r < 4; r++)
        qbuf[(quad * 4 + r) * 264 + o] = (bf16_t)(qa[j][r] + bv);
    }
  }
  __syncthreads();

  bf16x8 qf[8];
#pragma unroll
  for (int kk = 0; kk < 8; kk++)
    qf[kk] = *(const bf16x8*)(qbuf + l15 * 264 + kk * 32 + quad * 8);

  // phase 2: flash over this wave's segment
  f32x4 oacc[16];
#pragma unroll
  for (int ct = 0; ct < 16; ct++) oacc[ct] = (f32x4){0.f, 0.f, 0.f, 0.f};
  float mrun[4], lrun[4];
#pragma unroll
  for (int r = 0; r < 4; r++) { mrun[r] = -1e30f; lrun[r] = 0.f; }
  bf16_t* pw = pbuf[w];
  int nbeg = w * 576, nend = nbeg + 576;

  for (int n0 = nbeg; n0 < nend; n0 += 32) {
    f32x4 s0 = (f32x4){0.f, 0.f, 0.f, 0.f};
    f32x4 s1 = (f32x4){0.f, 0.f, 0.f, 0.f};
    const bf16_t* k0p = Kp + (size_t)(n0 + l15) * C1n + quad * 8;
    const bf16_t* k1p = k0p + 16 * C1n;
#pragma unroll
    for (int kk = 0; kk < 8; kk++) {
      s0 = MFMA16(qf[kk], *(const bf16x8*)(k0p + kk * 32), s0);
      s1 = MFMA16(qf[kk], *(const bf16x8*)(k1p + kk * 32), s1);
    }
    float mnew[4], alpha[4];
#pragma unroll
    for (int r = 0; r < 4; r++) {
      s0[r] *= 0.0625f;  // c1^-0.5
      s1[r] *= 0.0625f;
      float t = fmaxf(s0[r], s1[r]);
      t = fmaxf(t, __shfl_xor(t, 1));
      t = fmaxf(t, __shfl_xor(t, 2));
      t = fmaxf(t, __shfl_xor(t, 4));
      t = fmaxf(t, __shfl_xor(t, 8));
      mnew[r] = fmaxf(mrun[r], t);
      alpha[r] = exp2f((mrun[r] - mnew[r]) * L2E);
    }
#pragma unroll
    for (int r = 0; r < 4; r++) {
      s0[r] = exp2f((s0[r] - mnew[r]) * L2E);
      s1[r] = exp2f((s1[r] - mnew[r]) * L2E);
      float rsum = s0[r] + s1[r];
      rsum += __shfl_xor(rsum, 1);
      rsum += __shfl_xor(rsum, 2);
      rsum += __shfl_xor(rsum, 4);
      rsum += __shfl_xor(rsum, 8);
      lrun[r] = lrun[r] * alpha[r] + rsum;
      mrun[r] = mnew[r];
    }
#pragma unroll
    for (int ct = 0; ct < 16; ct++)
#pragma unroll
      for (int r = 0; r < 4; r++) oacc[ct][r] *= alpha[r];
#pragma unroll
    for (int r = 0; r < 4; r++) {
      pw[(quad * 4 + r) * 40 + l15] = (bf16_t)s0[r];
      pw[(quad * 4 + r) * 40 + 16 + l15] = (bf16_t)s1[r];
    }
    bf16x8 pa = *(const bf16x8*)(pw + l15 * 40 + quad * 8);
    const bf16_t* vbase = Vp + (size_t)l15 * Nn + n0 + quad * 8;
#pragma unroll
    for (int ct = 0; ct < 16; ct++) {
      bf16x8 vb = *(const bf16x8*)(vbase + (size_t)ct * 16 * Nn);
      oacc[ct] = MFMA16(pa, vb, oacc[ct]);
    }
  }

  // phase 3: cross-wave LSE merge
  if (l15 == 0) {
#pragma unroll
    for (int r = 0; r < 4; r++) {
      mlbuf[w][quad * 4 + r][0] = mrun[r];
      mlbuf[w][quad * 4 + r][1] = lrun[r];
    }
  }
  __syncthreads();
  float inv[4], scl[4];
#pragma unroll
  for (int r = 0; r < 4; r++) {
    int row = quad * 4 + r;
    float M = mlbuf[0][row][0];
    M = fmaxf(M, mlbuf[1][row][0]);
    M = fmaxf(M, mlbuf[2][row][0]);
    M = fmaxf(M, mlbuf[3][row][0]);
    float lt = 0.f;
#pragma unroll
    for (int w2 = 0; w2 < 4; w2++)
      lt += mlbuf[w2][row][1] * exp2f((mlbuf[w2][row][0] - M) * L2E);
    scl[r] = exp2f((mrun[r] - M) * L2E);
    inv[r] = 1.f / lt;
  }
#pragma unroll
  for (int ct = 0; ct < 16; ct++)
#pragma unroll
    for (int r = 0; r < 4; r++)
      obuf[w][(quad * 4 + r) * 264 + ct * 16 + l15] = (bf16_t)(oacc[ct][r] * scl[r]);
  __syncthreads();
#pragma unroll
  for (int cc = 0; cc < 4; cc++) {
    int ct = w * 4 + cc;
#pragma unroll
    for (int r = 0; r < 4; r++) {
      int idx = (quad * 4 + r) * 264 + ct * 16 + l15;
      float v = (float)obuf[0][idx] + (float)obuf[1][idx] +
                (float)obuf[2][idx] + (float)obuf[3][idx];
      ybuf[idx] = (bf16_t)(v * inv[r]);
    }
  }
  __syncthreads();

  // phase 4: W-conv, wave w handles o-tiles j = 2w, 2w+1
  const bf16_t* Wg = par + P_WW + (size_t)g * CGn * C2n;
  const bf16_t* wbias = par + P_WB + g * CGn;
  f32x4 wyacc[2];
  wyacc[0] = (f32x4){0.f, 0.f, 0.f, 0.f};
  wyacc[1] = (f32x4){0.f, 0.f, 0.f, 0.f};
#pragma unroll
  for (int kk = 0; kk < 8; kk++) {
    bf16x8 ya = *(const bf16x8*)(ybuf + l15 * 264 + kk * 32 + quad * 8);
#pragma unroll
    for (int jj = 0; jj < 2; jj++) {
      int j = w * 2 + jj;
      bf16x8 wv = *(const bf16x8*)(Wg + (size_t)(j * 16 + l15) * C2n + kk * 32 + quad * 8);
      wyacc[jj] = MFMA16(ya, wv, wyacc[jj]);
    }
  }
#pragma unroll
  for (int jj = 0; jj < 2; jj++) {
    int o = (w * 2 + jj) * 16 + l15;
    float bv = (float)wbias[o];
#pragma unroll
    for (int r = 0; r < 4; r++)
      wyBF[((size_t)b * Nn + m0 + quad * 4 + r) * 512 + g * 128 + o] =
          (bf16_t)(wyacc[jj][r] + bv);
  }
}

// ---------- wy BN stats (channel-last), f64 atomics ----------
__global__ __launch_bounds__(256) void k_wy_stats(const bf16_t* __restrict__ wyBF,
                                                  double* __restrict__ stats) {
  int b = blockIdx.y;
  int m0 = blockIdx.x * 256;
  int tid = threadIdx.x;
  double s0 = 0., q0 = 0., s1 = 0., q1 = 0.;
  const bf16_t* base = wyBF + ((size_t)b * Nn + m0) * 512;
  for (int i = 0; i < 256; i++) {
    double v0 = (double)(float)base[(size_t)i * 512 + tid];
    double v1 = (double)(float)base[(size_t)i * 512 + 256 + tid];
    s0 += v0; q0 += v0 * v0; s1 += v1; q1 += v1 * v1;
  }
  atomicAdd(&stats[tid], s0);
  atomicAdd(&stats[512 + tid], q0);
  atomicAdd(&stats[256 + tid], s1);
  atomicAdd(&stats[768 + tid], q1);
}

// ---------- BN scale/shift ----------
__global__ void k_bn_st(const double* __restrict__ stats, const bf16_t* __restrict__ gamma,
                        const bf16_t* __restrict__ beta, float* __restrict__ sArr,
                        float* __restrict__ tArr, double inv_count) {
  int ch = threadIdx.x;  // 512
  double mean = stats[ch] * inv_count;
  double var = stats[512 + ch] * inv_count - mean * mean;
  double s = (double)(float)gamma[ch] / sqrt(var + (double)EPS);
  sArr[ch] = (float)s;
  tArr[ch] = (float)((double)(float)beta[ch] - mean * s);
}

// ---------- fold wy-BN into bottleneck weights ----------
__global__ __launch_bounds__(256) void k_fold(
    const bf16_t* __restrict__ par, const float* __restrict__ sW,
    const float* __restrict__ tW, bf16_t* __restrict__ bcwF, float* __restrict__ biasF) {
  int oo = blockIdx.x;
  int tid = threadIdx.x;
  const bf16_t* row = par + P_BCW + (size_t)oo * 1024;
  bf16_t* orow = bcwF + (size_t)oo * 1024;
  float part = 0.f;
  for (int c = tid; c < 512; c += 256) orow[c] = row[c];
  for (int c = 512 + tid; c < 1024; c += 256) {
    float wv = (float)row[c];
    orow[c] = (bf16_t)(wv * sW[c - 512]);
    part += wv * tW[c - 512];
  }
  __shared__ float red[256];
  red[tid] = part;
  __syncthreads();
  for (int s = 128; s > 0; s >>= 1) {
    if (tid < s) red[tid] += red[tid + s];
    __syncthreads();
  }
  if (tid == 0) biasF[oo] = (float)par[P_BCB + oo] + red[0];
}

// ---------- final GEMM: mode 0 -> f64 atomic stats; mode 1 -> normalized f32 out ----------
__global__ __launch_bounds__(256) void k_final(
    const float* __restrict__ feats, const bf16_t* __restrict__ wyBF,
    const bf16_t* __restrict__ bcwF, const float* __restrict__ biasF,
    const float* __restrict__ sO, const float* __restrict__ tO,
    double* __restrict__ stats, float* __restrict__ out, int mode) {
  __shared__ alignas(16) bf16_t xsT[64][40];
  int b = blockIdx.z;
  int tid = threadIdx.x, w = tid >> 6, lane = tid & 63;
  int l15 = lane & 15, quad = lane >> 4;
  int oo0 = blockIdx.y * 64 + w * 16;
  int n0 = blockIdx.x * 64;

  f32x4 acc[4];
#pragma unroll
  for (int j = 0; j < 4; j++) acc[j] = (f32x4){0.f, 0.f, 0.f, 0.f};

  for (int kk = 0; kk < 16; kk++) {
    int c0 = kk * 32;
    __syncthreads();
#pragma unroll
    for (int i = 0; i < 8; i++) {
      int cc = i * 4 + w;
      xsT[lane][cc] = (bf16_t)feats[((size_t)b * Cn + c0 + cc) * Nn + n0 + lane];
    }
    __syncthreads();
    bf16x8 a = *(const bf16x8*)(bcwF + (size_t)(oo0 + l15) * 1024 + c0 + quad * 8);
#pragma unroll
    for (int j = 0; j < 4; j++) {
      bf16x8 bx = *(const bf16x8*)(&xsT[j * 16 + l15][quad * 8]);
      acc[j] = MFMA16(a, bx, acc[j]);
    }
  }
  for (int kk = 0; kk < 16; kk++) {
    int c0 = kk * 32;
    bf16x8 a = *(const bf16x8*)(bcwF + (size_t)(oo0 + l15) * 1024 + 512 + c0 + quad * 8);
#pragma unroll
    for (int j = 0; j < 4; j++) {
      bf16x8 bw = *(const bf16x8*)(wyBF + ((size_t)b * Nn + n0 + j * 16 + l15) * 512 + c0 + quad * 8);
      acc[j] = MFMA16(a, bw, acc[j]);
    }
  }

  if (mode == 0) {
#pragma unroll
    for (int r = 0; r < 4; r++) {
      int row = oo0 + quad * 4 + r;
      float bv = biasF[row];
      float s = 0.f, q = 0.f;
#pragma unroll
      for (int j = 0; j < 4; j++) {
        float v = acc[j][r] + bv;
        s += v; q += v * v;
      }
      s += __shfl_xor(s, 1); q += __shfl_xor(q, 1);
      s += __shfl_xor(s, 2); q += __shfl_xor(q, 2);
      s += __shfl_xor(s, 4); q += __shfl_xor(q, 4);
      s += __shfl_xor(s, 8); q += __shfl_xor(q, 8);
      if (l15 == 0) {
        atomicAdd(&stats[row], (double)s);
        atomicAdd(&stats[512 + row], (double)q);
      }
    }
  } else {
#pragma unroll
    for (int r = 0; r < 4; r++) {
      int row = oo0 + quad * 4 + r;
      float bv = biasF[row];
      float sc = sO[row], tc = tO[row];
#pragma unroll
      for (int j = 0; j < 4; j++)
        out[((size_t)b * 512 + row) * Nn + n0 + j * 16 + l15] =
            (acc[j][r] + bv) * sc + tc;
    }
  }
}

extern "C" void kernel_launch(void* const* d_in, const int* in_sizes, int n_in,
                              void* d_out, int out_size, void* d_ws, size_t ws_size,
                              hipStream_t stream) {
  const float* feats = (const float*)d_in[0];

  char* ws = (char*)d_ws;
  bf16_t* WPAR = (bf16_t*)(ws + OFF_WPAR);
  float* biasF = (float*)(ws + OFF_BIASF);
  float* sW = (float*)(ws + OFF_SW);
  float* tW = (float*)(ws + OFF_TW2);
  float* sO = (float*)(ws + OFF_SO);
  float* tO = (float*)(ws + OFF_TO);
  double* statsWy = (double*)(ws + OFF_STATW);
  double* statsO = (double*)(ws + OFF_STATO);
  bf16_t* wyBF = (bf16_t*)(ws + OFF_WY);
  bf16_t* KV = (bf16_t*)(ws + OFF_KV);
  bf16_t* bcwF = (bf16_t*)(ws + OFF_KV);  // overlay: KV dead before k_fold

  // adaptive concurrency from available workspace (constant per session -> graph-safe)
  size_t avail = (ws_size > OFF_KV) ? ws_size - OFF_KV : KVS_BYTES;
  int n_conc = (int)(avail / KVS_BYTES);
  if (n_conc < 1) n_conc = 1;
  if (n_conc > 32) n_conc = 32;

  static const unsigned par_off[14] = {
      (unsigned)P_TW, (unsigned)P_TB, (unsigned)P_PW, (unsigned)P_PB,
      (unsigned)P_GW, (unsigned)P_GB, (unsigned)P_WW, (unsigned)P_WB,
      (unsigned)P_WG, (unsigned)P_WBE, (unsigned)P_BCW, (unsigned)P_BCB,
      (unsigned)P_BCG, (unsigned)P_BCBE};
  WArgs wa;
  for (int i = 0; i < 14; i++) {
    wa.src[i] = (const float*)d_in[i + 1];
    wa.n[i] = (unsigned)in_sizes[i + 1];
    wa.off[i] = par_off[i];
  }

  hipMemsetAsync(ws + OFF_STATW, 0, 16384, stream);  // statsWy + statsO

  k_wconv<<<dim3(256, 14), 256, 0, stream>>>(wa, WPAR);
  for (int base = 0; base < 32; base += n_conc) {
    int cnt = (32 - base < n_conc) ? (32 - base) : n_conc;
    k_proj_k<<<dim3(36, 4, cnt), 256, 0, stream>>>(feats, WPAR, KV, base);
    k_proj_v<<<dim3(36, 4, cnt), 256, 0, stream>>>(feats, WPAR, KV, base);
    k_attn_wy<<<dim3(144, cnt), 256, 0, stream>>>(feats, KV, WPAR, wyBF, base);
  }
  k_wy_stats<<<dim3(9, 8), 256, 0, stream>>>(wyBF, statsWy);
  k_bn_st<<<1, 512, 0, stream>>>(statsWy, WPAR + P_WG, WPAR + P_WBE, sW, tW, 1.0 / 18432.0);
  k_fold<<<512, 256, 0, stream>>>(WPAR, sW, tW, bcwF, biasF);
  k_final<<<dim3(36, 8, 8), 256, 0, stream>>>(feats, wyBF, bcwF, biasF, sO, tO, statsO,
                                              (float*)d_out, 0);
  k_bn_st<<<1, 512, 0, stream>>>(statsO, WPAR + P_BCG, WPAR + P_BCBE, sO, tO, 1.0 / 18432.0);
  k_final<<<dim3(36, 8, 8), 256, 0, stream>>>(feats, wyBF, bcwF, biasF, sO, tO, statsO,
                                              (float*)d_out, 1);
}